// Round 6
// baseline (3060.190 us; speedup 1.0000x reference)
//
#include <hip/hip_runtime.h>
#include <math.h>
#include <stdint.h>

// UpsampleFlow3: fused exact 5-NN + softmax(-dist) + weighted flow sum.
// B=4, N=16384, M=4096, K=5, fp32.
//
// Round-6: sort QUERIES by cell as well as points. Waves then hold 64
// spatially-adjacent queries and scan a wave-uniform candidate stream
// (scalar s_load cell meta + point float4) over the ring-expanded bounding
// box of the wave's query cells. r5's 24%-VALUBusy / 11%-occupancy
// latency-bound per-lane gathers become r3-style uniform-stream issue-bound
// work, but over ~100-350 candidates instead of 4096.
// Exactness: u64 (d2bits,idx) keys (jax tie rule); stop bound r*h validated
// in r4/r5; per-lane superset guarantee -> bit-stable output under atomic
// permutation of grouping.

typedef unsigned int u32;
typedef unsigned long long u64;

#define KNN 5

__device__ __forceinline__ float get_inv_sigma(const int* __restrict__ rf) {
    const int ri = rf[0];
    const float sigma = (ri >= 1 && ri <= 1000000) ? (float)ri : __int_as_float(ri);
    return 1.0f / sigma;          // INITIAL_RADIUS = 1.0
}

__device__ __forceinline__ void cell_of_rt(float x, float y, float z,
                                           const float4 o, const float invh, int G,
                                           int& cx, int& cy, int& cz) {
    cx = (int)floorf((x - o.x) * invh);
    cy = (int)floorf((y - o.y) * invh);
    cz = (int)floorf((z - o.z) * invh);
    cx = min(max(cx, 0), G - 1);
    cy = min(max(cy, 0), G - 1);
    cz = min(max(cz, 0), G - 1);
}

// ---------------- prep: zero + bbox ----------------
__global__ __launch_bounds__(256)
void zero_bbox_kernel(const float* __restrict__ sxyz, const int* __restrict__ rf,
                      int M, int G, int G3, float4* __restrict__ bbox,
                      u32* __restrict__ meta, u32* __restrict__ cursor,
                      u32* __restrict__ qmeta) {
    const int b = blockIdx.x, tid = threadIdx.x;
    for (int i = tid; i < G3; i += 256) {
        meta[b * G3 + i] = 0u; cursor[b * G3 + i] = 0u; qmeta[b * G3 + i] = 0u;
    }
    const float inv = get_inv_sigma(rf);
    const float* sb = sxyz + (size_t)b * 3 * M;
    float mnx = 1e30f, mny = 1e30f, mnz = 1e30f;
    float mxx = -1e30f, mxy = -1e30f, mxz = -1e30f;
    for (int i = tid; i < M; i += 256) {
        const float x = sb[i] * inv, y = sb[M + i] * inv, z = sb[2 * M + i] * inv;
        mnx = fminf(mnx, x); mxx = fmaxf(mxx, x);
        mny = fminf(mny, y); mxy = fmaxf(mxy, y);
        mnz = fminf(mnz, z); mxz = fmaxf(mxz, z);
    }
    __shared__ float red[6][256];
    red[0][tid] = mnx; red[1][tid] = mny; red[2][tid] = mnz;
    red[3][tid] = mxx; red[4][tid] = mxy; red[5][tid] = mxz;
    __syncthreads();
    for (int s = 128; s > 0; s >>= 1) {
        if (tid < s) {
            red[0][tid] = fminf(red[0][tid], red[0][tid + s]);
            red[1][tid] = fminf(red[1][tid], red[1][tid + s]);
            red[2][tid] = fminf(red[2][tid], red[2][tid + s]);
            red[3][tid] = fmaxf(red[3][tid], red[3][tid + s]);
            red[4][tid] = fmaxf(red[4][tid], red[4][tid + s]);
            red[5][tid] = fmaxf(red[5][tid], red[5][tid + s]);
        }
        __syncthreads();
    }
    if (tid == 0) {
        const float ox = red[0][0], oy = red[1][0], oz = red[2][0];
        const float ext = fmaxf(fmaxf(red[3][0] - ox, red[4][0] - oy), red[5][0] - oz);
        const float h = ext * (1.0f + 2e-5f) / (float)G + 1e-20f;
        bbox[2 * b + 0] = make_float4(ox, oy, oz, h);
        bbox[2 * b + 1] = make_float4(1.0f / h, 0.f, 0.f, 0.f);
    }
}

// ---------------- prep: count points + queries (fused) ----------------
__global__ __launch_bounds__(256)
void count_all_kernel(const float* __restrict__ sxyz, const float* __restrict__ xyz,
                      const int* __restrict__ rf, int M, int N, int B, int G, int G3,
                      const float4* __restrict__ bbox,
                      u32* __restrict__ meta, u32* __restrict__ qmeta) {
    int t = blockIdx.x * 256 + threadIdx.x;
    const float inv = get_inv_sigma(rf);
    const int PT = B * M;
    if (t < PT) {
        const int b = t / M, m = t - b * M;
        const float* sb = sxyz + (size_t)b * 3 * M;
        const float x = sb[m] * inv, y = sb[M + m] * inv, z = sb[2 * M + m] * inv;
        const float4 o = bbox[2 * b]; const float invh = bbox[2 * b + 1].x;
        int cx, cy, cz; cell_of_rt(x, y, z, o, invh, G, cx, cy, cz);
        atomicAdd(&meta[b * G3 + (cz * G + cy) * G + cx], 1u);
    } else {
        t -= PT;
        if (t >= B * N) return;
        const int b = t / N, q = t - b * N;
        const float* qb = xyz + (size_t)b * 3 * N;
        const float x = qb[q] * inv, y = qb[N + q] * inv, z = qb[2 * N + q] * inv;
        const float4 o = bbox[2 * b]; const float invh = bbox[2 * b + 1].x;
        int cx, cy, cz; cell_of_rt(x, y, z, o, invh, G, cx, cy, cz);
        atomicAdd(&qmeta[b * G3 + (cz * G + cy) * G + cx], 1u);
    }
}

// ---------------- prep: scan both tables (fused) ----------------
// blocks 0..B-1: meta (write packed (start<<16)|cnt, cursor=start)
// blocks B..2B-1: qmeta in-place -> exclusive start
__global__ __launch_bounds__(256)
void scan_all_kernel(u32* __restrict__ meta, u32* __restrict__ cursor,
                     u32* __restrict__ qmeta, int G3, int B) {
    const int idx = blockIdx.x, tid = threadIdx.x;
    const bool isQ = idx >= B;
    const int b = isQ ? idx - B : idx;
    u32* arr = (isQ ? qmeta : meta) + b * G3;
    u32* cur = isQ ? nullptr : cursor + b * G3;
    __shared__ u32 tmp[256];
    __shared__ u32 carry;
    if (tid == 0) carry = 0u;
    __syncthreads();
    for (int base = 0; base < G3; base += 256) {       // G3 % 256 == 0
        const u32 c = arr[base + tid];
        tmp[tid] = c;
        __syncthreads();
        for (int s = 1; s < 256; s <<= 1) {
            u32 v = (tid >= s) ? tmp[tid - s] : 0u;
            __syncthreads();
            tmp[tid] += v;
            __syncthreads();
        }
        const u32 start = carry + tmp[tid] - c;        // exclusive
        if (isQ) arr[base + tid] = start;
        else { arr[base + tid] = (start << 16) | c; cur[base + tid] = start; }
        __syncthreads();
        if (tid == 255) carry += tmp[255];
        __syncthreads();
    }
}

// ---------------- prep: scatter points + queries (fused) ----------------
__global__ __launch_bounds__(256)
void scatter_all_kernel(const float* __restrict__ sxyz, const float* __restrict__ xyz,
                        const int* __restrict__ rf, int M, int N, int B, int G, int G3,
                        const float4* __restrict__ bbox,
                        u32* __restrict__ cursor, u32* __restrict__ qmeta,
                        float4* __restrict__ pts, u32* __restrict__ qorder) {
    int t = blockIdx.x * 256 + threadIdx.x;
    const float inv = get_inv_sigma(rf);
    const int PT = B * M;
    if (t < PT) {
        const int b = t / M, m = t - b * M;
        const float* sb = sxyz + (size_t)b * 3 * M;
        const float x = sb[m] * inv, y = sb[M + m] * inv, z = sb[2 * M + m] * inv;
        const float4 o = bbox[2 * b]; const float invh = bbox[2 * b + 1].x;
        int cx, cy, cz; cell_of_rt(x, y, z, o, invh, G, cx, cy, cz);
        const u32 pos = atomicAdd(&cursor[b * G3 + (cz * G + cy) * G + cx], 1u);
        pts[(size_t)b * M + pos] = make_float4(x, y, z, __uint_as_float((u32)m));
    } else {
        t -= PT;
        if (t >= B * N) return;
        const int b = t / N, q = t - b * N;
        const float* qb = xyz + (size_t)b * 3 * N;
        const float x = qb[q] * inv, y = qb[N + q] * inv, z = qb[2 * N + q] * inv;
        const float4 o = bbox[2 * b]; const float invh = bbox[2 * b + 1].x;
        int cx, cy, cz; cell_of_rt(x, y, z, o, invh, G, cx, cy, cz);
        const u32 pos = atomicAdd(&qmeta[b * G3 + (cz * G + cy) * G + cx], 1u);
        qorder[(size_t)b * N + pos] = (u32)q;
    }
}

// ---------------- search: sorted queries, wave-uniform candidate stream ----------------

#define CEK_FULL(k, c) { const bool sw_ = (c) < (k); const u64 mn_ = sw_ ? (c) : (k); \
                         const u64 mx_ = sw_ ? (k) : (c); (k) = mn_; (c) = mx_; }
#define CEK_LAST(k, c) { (k) = ((c) < (k)) ? (c) : (k); }

#define PROC_CAND(p) {                                                        \
    float t_ = qx * (p).x; t_ = fmaf(qy, (p).y, t_); t_ = fmaf(qz, (p).z, t_);\
    const float pw_ = fmaf((p).x, (p).x, fmaf((p).y, (p).y, (p).z * (p).z));  \
    const float dc_ = fmaxf(fmaf(-2.0f, t_, qq + pw_), 1e-12f);               \
    u64 c_ = ((u64)__float_as_uint(dc_) << 32) | (u64)__float_as_uint((p).w); \
    CEK_FULL(k0, c_) CEK_FULL(k1, c_) CEK_FULL(k2, c_) CEK_FULL(k3, c_)       \
    CEK_LAST(k4, c_) }

#define KEY_INIT (((u64)0x7F7FFFFFu) << 32)   // (FLT_MAX, idx 0)

__global__ __launch_bounds__(256)
void sorted_search_kernel(const float* __restrict__ xyz,
                          const float* __restrict__ sflow,
                          const int* __restrict__ rf,
                          const float4* __restrict__ bbox,
                          const u32* __restrict__ meta,
                          const float4* __restrict__ pts,
                          const u32* __restrict__ qorder,
                          float* __restrict__ out,
                          int N, int M, int G, int G3, int bpB) {
    const int lane = threadIdx.x & 63;
    const int wid  = threadIdx.x >> 6;
    const int g    = blockIdx.x * 4 + wid;       // query group (64 sorted queries)
    const int b    = g / bpB;
    const int gi   = g - b * bpB;
    const u32 n    = qorder[(size_t)b * N + gi * 64 + lane];

    const float inv = get_inv_sigma(rf);
    const float* qb = xyz + (size_t)b * 3 * N;
    const float qx = qb[n] * inv;
    const float qy = qb[N + n] * inv;
    const float qz = qb[2 * N + n] * inv;
    const float qq = fmaf(qx, qx, fmaf(qy, qy, qz * qz));

    const float4 o   = bbox[2 * b];
    const float invh = bbox[2 * b + 1].x;
    const float h    = o.w;
    int qcx, qcy, qcz; cell_of_rt(qx, qy, qz, o, invh, G, qcx, qcy, qcz);

    // wave bounding box of query cells (butterfly reduce, then SGPR)
    int lx = qcx, hx = qcx, ly = qcy, hy = qcy, lz = qcz, hz = qcz;
#pragma unroll
    for (int off = 32; off > 0; off >>= 1) {
        lx = min(lx, __shfl_xor(lx, off, 64)); hx = max(hx, __shfl_xor(hx, off, 64));
        ly = min(ly, __shfl_xor(ly, off, 64)); hy = max(hy, __shfl_xor(hy, off, 64));
        lz = min(lz, __shfl_xor(lz, off, 64)); hz = max(hz, __shfl_xor(hz, off, 64));
    }
    lx = __builtin_amdgcn_readfirstlane(lx); hx = __builtin_amdgcn_readfirstlane(hx);
    ly = __builtin_amdgcn_readfirstlane(ly); hy = __builtin_amdgcn_readfirstlane(hy);
    lz = __builtin_amdgcn_readfirstlane(lz); hz = __builtin_amdgcn_readfirstlane(hz);

    const u32* __restrict__ mb = meta + b * G3;
    const float4* __restrict__ pb = pts + (size_t)b * M;

    u64 k0 = KEY_INIT, k1 = KEY_INIT, k2 = KEY_INIT, k3 = KEY_INIT, k4 = KEY_INIT;
    const float margin = 1e-3f + 1e-5f * qq;

    for (int r = 0; r <= G; ++r) {
        const int ex0 = max(lx - r, 0), ex1 = min(hx + r, G - 1);
        const int ey0 = max(ly - r, 0), ey1 = min(hy + r, G - 1);
        const int ez0 = max(lz - r, 0), ez1 = min(hz + r, G - 1);
        const int px0 = lx - r + 1, px1 = hx + r - 1;   // prev (r-1) unclipped;
        const int py0 = ly - r + 1, py1 = hy + r - 1;   // clipped cells inside
        const int pz0 = lz - r + 1, pz1 = hz + r - 1;   // prev box also skip ok
        for (int cz = ez0; cz <= ez1; ++cz) {
            const bool zin = (cz >= pz0 && cz <= pz1);
            for (int cy = ey0; cy <= ey1; ++cy) {
                const bool yin = zin && (cy >= py0 && cy <= py1);
                for (int cx = ex0; cx <= ex1; ++cx) {
                    if (r > 0 && yin && cx >= px0 && cx <= px1) continue; // scanned
                    const u32 mc = mb[(cz * G + cy) * G + cx];  // uniform s_load
                    const u32 cnt = mc & 0xFFFFu;
                    if (!cnt) continue;
                    const u32 st = mc >> 16;
                    u32 i = 0;
                    for (; i + 2 <= cnt; i += 2) {
                        const float4 pa = pb[st + i];
                        const float4 pc = pb[st + i + 1];
                        PROC_CAND(pa)
                        PROC_CAND(pc)
                    }
                    if (i < cnt) { const float4 pa = pb[st + i]; PROC_CAND(pa) }
                }
            }
        }
        // uniform stop: all lanes' own 5th-best beats distance to unscanned
        const float own = __uint_as_float((u32)(k4 >> 32));
        const float bound = (float)r * h;
        if (__all(own < bound * bound - margin)) break;
    }

    // ---- exact epilogue, per lane ----
    const float d0 = sqrtf(__uint_as_float((u32)(k0 >> 32)));
    const float d1 = sqrtf(__uint_as_float((u32)(k1 >> 32)));
    const float d2 = sqrtf(__uint_as_float((u32)(k2 >> 32)));
    const float d3 = sqrtf(__uint_as_float((u32)(k3 >> 32)));
    const float d4 = sqrtf(__uint_as_float((u32)(k4 >> 32)));
    const float w0 = expf(d0 - d0);
    const float w1 = expf(d0 - d1);
    const float w2 = expf(d0 - d2);
    const float w3 = expf(d0 - d3);
    const float w4 = expf(d0 - d4);
    const float inv_wsum = 1.0f / (w0 + w1 + w2 + w3 + w4);

    const u32 i0 = (u32)k0, i1 = (u32)k1, i2 = (u32)k2, i3 = (u32)k3, i4 = (u32)k4;
    const float* fb = sflow + (size_t)b * 3 * M;
    float ax = 0.f, ay = 0.f, az = 0.f;
    ax = fmaf(w0, fb[i0], ax); ay = fmaf(w0, fb[M + i0], ay); az = fmaf(w0, fb[2 * M + i0], az);
    ax = fmaf(w1, fb[i1], ax); ay = fmaf(w1, fb[M + i1], ay); az = fmaf(w1, fb[2 * M + i1], az);
    ax = fmaf(w2, fb[i2], ax); ay = fmaf(w2, fb[M + i2], ay); az = fmaf(w2, fb[2 * M + i2], az);
    ax = fmaf(w3, fb[i3], ax); ay = fmaf(w3, fb[M + i3], ay); az = fmaf(w3, fb[2 * M + i3], az);
    ax = fmaf(w4, fb[i4], ax); ay = fmaf(w4, fb[M + i4], ay); az = fmaf(w4, fb[2 * M + i4], az);

    float* ob = out + (size_t)b * 3 * N;
    ob[n]         = ax * inv_wsum;
    ob[N + n]     = ay * inv_wsum;
    ob[2 * N + n] = az * inv_wsum;
}

// ---------------- brute-force fallback (r3 structure, no workspace) ----------------

#define CE_FULL(k, ki, c, ci)                          \
    {                                                  \
        const bool sw = (c) < (k);                     \
        const float vmn = fminf(k, c);                 \
        const float vmx = fmaxf(k, c);                 \
        const u32 nki = sw ? (ci) : (ki);              \
        const u32 nci = sw ? (ki) : (ci);              \
        (k) = vmn; (c) = vmx; (ki) = nki; (ci) = nci;  \
    }
#define CE_LAST(k, ki, c, ci)                          \
    {                                                  \
        const bool sw = (c) < (k);                     \
        (ki) = sw ? (ci) : (ki);                       \
        (k) = fminf(k, c);                             \
    }

#define BSLICES 8
__global__ __launch_bounds__(512)
void brute_kernel(const float* __restrict__ xyz, const float* __restrict__ sxyz,
                  const float* __restrict__ sflow, const int* __restrict__ rf,
                  float* __restrict__ out, int N, int M, int bpB) {
    __shared__ float sval_d[BSLICES * KNN * 64];
    __shared__ u32   sval_i[BSLICES * KNN * 64];
    const int tid = threadIdx.x, lane = tid & 63, wid = tid >> 6;
    const int swid = __builtin_amdgcn_readfirstlane(wid);
    const int b = blockIdx.x / bpB;
    const int n = (blockIdx.x % bpB) * 64 + lane;
    const float inv = get_inv_sigma(rf);
    const float* qb = xyz + (size_t)b * 3 * N;
    const float qx = qb[n] * inv, qy = qb[N + n] * inv, qz = qb[2 * N + n] * inv;
    const float qq = fmaf(qx, qx, fmaf(qy, qy, qz * qz));
    const int CH = M / BSLICES, j0 = swid * CH;
    const float* sb = sxyz + (size_t)b * 3 * M;
    float e0 = 1e30f, e1 = 1e30f, e2 = 1e30f, e3 = 1e30f, e4 = 1e30f;
    u32 i0 = 0, i1 = 0, i2 = 0, i3 = 0, i4 = 0;
    for (int j = 0; j < CH; ++j) {
        const float px = sb[j0 + j] * inv;
        const float py = sb[M + j0 + j] * inv;
        const float pz = sb[2 * M + j0 + j] * inv;
        const float pw = fmaf(px, px, fmaf(py, py, pz * pz));
        float t = qx * px; t = fmaf(qy, py, t); t = fmaf(qz, pz, t);
        float c = fmaf(-2.0f, t, pw);
        u32 ci = (u32)(j0 + j);
        CE_FULL(e0, i0, c, ci) CE_FULL(e1, i1, c, ci) CE_FULL(e2, i2, c, ci)
        CE_FULL(e3, i3, c, ci) CE_LAST(e4, i4, c, ci)
    }
    sval_d[(wid * KNN + 0) * 64 + lane] = e0;  sval_i[(wid * KNN + 0) * 64 + lane] = i0;
    sval_d[(wid * KNN + 1) * 64 + lane] = e1;  sval_i[(wid * KNN + 1) * 64 + lane] = i1;
    sval_d[(wid * KNN + 2) * 64 + lane] = e2;  sval_i[(wid * KNN + 2) * 64 + lane] = i2;
    sval_d[(wid * KNN + 3) * 64 + lane] = e3;  sval_i[(wid * KNN + 3) * 64 + lane] = i3;
    sval_d[(wid * KNN + 4) * 64 + lane] = e4;  sval_i[(wid * KNN + 4) * 64 + lane] = i4;
    __syncthreads();
    if (wid == 0) {
        float m0 = 1e30f, m1 = 1e30f, m2 = 1e30f, m3 = 1e30f, m4 = 1e30f;
        u32 g0 = 0, g1 = 0, g2 = 0, g3 = 0, g4 = 0;
#pragma unroll
        for (int w = 0; w < BSLICES; ++w)
#pragma unroll
            for (int k = 0; k < KNN; ++k) {
                float c = sval_d[(w * KNN + k) * 64 + lane];
                u32 ci = sval_i[(w * KNN + k) * 64 + lane];
                CE_FULL(m0, g0, c, ci) CE_FULL(m1, g1, c, ci) CE_FULL(m2, g2, c, ci)
                CE_FULL(m3, g3, c, ci) CE_LAST(m4, g4, c, ci)
            }
        const float d0 = sqrtf(fmaxf(m0 + qq, 1e-12f));
        const float d1 = sqrtf(fmaxf(m1 + qq, 1e-12f));
        const float d2 = sqrtf(fmaxf(m2 + qq, 1e-12f));
        const float d3 = sqrtf(fmaxf(m3 + qq, 1e-12f));
        const float d4 = sqrtf(fmaxf(m4 + qq, 1e-12f));
        const float w0 = expf(d0 - d0), w1 = expf(d0 - d1), w2 = expf(d0 - d2);
        const float w3 = expf(d0 - d3), w4 = expf(d0 - d4);
        const float inv_wsum = 1.0f / (w0 + w1 + w2 + w3 + w4);
        const float* fb = sflow + (size_t)b * 3 * M;
        float ax = 0.f, ay = 0.f, az = 0.f;
        ax = fmaf(w0, fb[g0], ax); ay = fmaf(w0, fb[M + g0], ay); az = fmaf(w0, fb[2 * M + g0], az);
        ax = fmaf(w1, fb[g1], ax); ay = fmaf(w1, fb[M + g1], ay); az = fmaf(w1, fb[2 * M + g1], az);
        ax = fmaf(w2, fb[g2], ax); ay = fmaf(w2, fb[M + g2], ay); az = fmaf(w2, fb[2 * M + g2], az);
        ax = fmaf(w3, fb[g3], ax); ay = fmaf(w3, fb[M + g3], ay); az = fmaf(w3, fb[2 * M + g3], az);
        ax = fmaf(w4, fb[g4], ax); ay = fmaf(w4, fb[M + g4], ay); az = fmaf(w4, fb[2 * M + g4], az);
        float* ob = out + (size_t)b * 3 * N;
        ob[n] = ax * inv_wsum;
        ob[N + n] = ay * inv_wsum;
        ob[2 * N + n] = az * inv_wsum;
    }
}

extern "C" void kernel_launch(void* const* d_in, const int* in_sizes, int n_in,
                              void* d_out, int out_size, void* d_ws, size_t ws_size,
                              hipStream_t stream) {
    const float* xyz   = (const float*)d_in[0];
    const float* sxyz  = (const float*)d_in[1];
    const float* sflow = (const float*)d_in[2];
    const int*   rf    = (const int*)d_in[3];
    // d_in[4] = K; fixed at 5 (KNN).

    const int B = 4;
    const int N = in_sizes[0] / (3 * B);    // 16384
    const int M = in_sizes[1] / (3 * B);    // 4096
    float* out = (float*)d_out;
    const int bpB = N / 64;                 // 256

    // pick grid resolution by workspace budget; G3 must be divisible by 256
    int G = 0;
    {
        const int cand[2] = {24, 16};       // 13824, 4096 cells
        for (int ci = 0; ci < 2; ++ci) {
            const int g = cand[ci];
            const size_t g3 = (size_t)g * g * g;
            const size_t need = 128 + 3 * ((size_t)B * g3 * 4)
                              + (size_t)B * M * 16 + (size_t)B * N * 4;
            if (ws_size >= need) { G = g; break; }
        }
    }

    if (G > 0 && M <= 65535 && N <= 65535) {
        const int G3 = G * G * G;
        char* w = (char*)d_ws;
        float4* bbox   = (float4*)w;                     w += 128;
        u32*    meta   = (u32*)w;                        w += (size_t)B * G3 * 4;
        u32*    cursor = (u32*)w;                        w += (size_t)B * G3 * 4;
        u32*    qmeta  = (u32*)w;                        w += (size_t)B * G3 * 4;
        float4* pts    = (float4*)w;                     w += (size_t)B * M * 16;
        u32*    qorder = (u32*)w;

        const int totalCQ = B * (M + N);
        zero_bbox_kernel<<<dim3(B), dim3(256), 0, stream>>>(sxyz, rf, M, G, G3,
                                                            bbox, meta, cursor, qmeta);
        count_all_kernel<<<dim3((totalCQ + 255) / 256), dim3(256), 0, stream>>>(
            sxyz, xyz, rf, M, N, B, G, G3, bbox, meta, qmeta);
        scan_all_kernel<<<dim3(2 * B), dim3(256), 0, stream>>>(meta, cursor, qmeta, G3, B);
        scatter_all_kernel<<<dim3((totalCQ + 255) / 256), dim3(256), 0, stream>>>(
            sxyz, xyz, rf, M, N, B, G, G3, bbox, cursor, qmeta, pts, qorder);
        const int nGroups = B * bpB;                     // 1024
        sorted_search_kernel<<<dim3(nGroups / 4), dim3(256), 0, stream>>>(
            xyz, sflow, rf, bbox, meta, pts, qorder, out, N, M, G, G3, bpB);
    } else {
        brute_kernel<<<dim3(B * bpB), dim3(512), 0, stream>>>(xyz, sxyz, sflow, rf, out, N, M, bpB);
    }
}

// Round 7
// 1376.130 us; speedup vs baseline: 2.2238x; 2.2238x over previous
//
#include <hip/hip_runtime.h>
#include <math.h>
#include <stdint.h>

// UpsampleFlow3: fused exact 5-NN + softmax(-dist) + weighted flow sum.
// B=4, N=16384, M=4096, K=5, fp32.
//
// Round-7: Morton-ordered query groups. r6 failed because raster-sorted
// query groups straddle rows -> wave cell-bbox spanned the full x-range ->
// thousands of cells/wave + 4 waves/CU -> 2.4% VALUBusy stragglers.
// Fixes: (a) queries counting-sorted by MORTON cell code (compact 64-query
// groups); (b) 4 slice-waves per group (stripe cells uniformly, per-slice
// deterministic stop, LDS merge) -> 16 waves/CU; (c) all meta/point loads
// wave-uniform scalar; in-wave control flow fully uniform.
// Exactness: u64 (d2bits,idx) keys; per-slice stop bound r*h (r5-validated).

typedef unsigned int u32;
typedef unsigned long long u64;

#define KNN 5

__device__ __forceinline__ float get_inv_sigma(const int* __restrict__ rf) {
    const int ri = rf[0];
    const float sigma = (ri >= 1 && ri <= 1000000) ? (float)ri : __int_as_float(ri);
    return 1.0f / sigma;          // INITIAL_RADIUS = 1.0
}

__device__ __forceinline__ void cell_of_rt(float x, float y, float z,
                                           const float4 o, const float invh, int G,
                                           int& cx, int& cy, int& cz) {
    cx = (int)floorf((x - o.x) * invh);
    cy = (int)floorf((y - o.y) * invh);
    cz = (int)floorf((z - o.z) * invh);
    cx = min(max(cx, 0), G - 1);
    cy = min(max(cy, 0), G - 1);
    cz = min(max(cz, 0), G - 1);
}

// spread low 5 bits to positions 0,3,6,9,12 (G <= 32)
__device__ __forceinline__ u32 spread5(u32 v) {
    u32 r = (v & 1u);
    r |= (v & 2u) << 2;
    r |= (v & 4u) << 4;
    r |= (v & 8u) << 6;
    r |= (v & 16u) << 8;
    return r;
}
__device__ __forceinline__ u32 morton3(int cx, int cy, int cz) {
    return spread5((u32)cx) | (spread5((u32)cy) << 1) | (spread5((u32)cz) << 2);
}

// ---------------- prep: zero + bbox ----------------
__global__ __launch_bounds__(256)
void zero_bbox_kernel(const float* __restrict__ sxyz, const int* __restrict__ rf,
                      int M, int G, int G3, float4* __restrict__ bbox,
                      u32* __restrict__ meta, u32* __restrict__ cursor,
                      u32* __restrict__ qmeta) {
    const int b = blockIdx.x, tid = threadIdx.x;
    for (int i = tid; i < G3; i += 256) {
        meta[b * G3 + i] = 0u; cursor[b * G3 + i] = 0u; qmeta[b * G3 + i] = 0u;
    }
    const float inv = get_inv_sigma(rf);
    const float* sb = sxyz + (size_t)b * 3 * M;
    float mnx = 1e30f, mny = 1e30f, mnz = 1e30f;
    float mxx = -1e30f, mxy = -1e30f, mxz = -1e30f;
    for (int i = tid; i < M; i += 256) {
        const float x = sb[i] * inv, y = sb[M + i] * inv, z = sb[2 * M + i] * inv;
        mnx = fminf(mnx, x); mxx = fmaxf(mxx, x);
        mny = fminf(mny, y); mxy = fmaxf(mxy, y);
        mnz = fminf(mnz, z); mxz = fmaxf(mxz, z);
    }
    __shared__ float red[6][256];
    red[0][tid] = mnx; red[1][tid] = mny; red[2][tid] = mnz;
    red[3][tid] = mxx; red[4][tid] = mxy; red[5][tid] = mxz;
    __syncthreads();
    for (int s = 128; s > 0; s >>= 1) {
        if (tid < s) {
            red[0][tid] = fminf(red[0][tid], red[0][tid + s]);
            red[1][tid] = fminf(red[1][tid], red[1][tid + s]);
            red[2][tid] = fminf(red[2][tid], red[2][tid + s]);
            red[3][tid] = fmaxf(red[3][tid], red[3][tid + s]);
            red[4][tid] = fmaxf(red[4][tid], red[4][tid + s]);
            red[5][tid] = fmaxf(red[5][tid], red[5][tid + s]);
        }
        __syncthreads();
    }
    if (tid == 0) {
        const float ox = red[0][0], oy = red[1][0], oz = red[2][0];
        const float ext = fmaxf(fmaxf(red[3][0] - ox, red[4][0] - oy), red[5][0] - oz);
        const float h = ext * (1.0f + 2e-5f) / (float)G + 1e-20f;
        bbox[2 * b + 0] = make_float4(ox, oy, oz, h);
        bbox[2 * b + 1] = make_float4(1.0f / h, 0.f, 0.f, 0.f);
    }
}

// ---------------- prep: count points (linear idx) + queries (morton idx) ----------------
__global__ __launch_bounds__(256)
void count_all_kernel(const float* __restrict__ sxyz, const float* __restrict__ xyz,
                      const int* __restrict__ rf, int M, int N, int B, int G, int G3,
                      const float4* __restrict__ bbox,
                      u32* __restrict__ meta, u32* __restrict__ qmeta) {
    int t = blockIdx.x * 256 + threadIdx.x;
    const float inv = get_inv_sigma(rf);
    const int PT = B * M;
    if (t < PT) {
        const int b = t / M, m = t - b * M;
        const float* sb = sxyz + (size_t)b * 3 * M;
        const float x = sb[m] * inv, y = sb[M + m] * inv, z = sb[2 * M + m] * inv;
        const float4 o = bbox[2 * b]; const float invh = bbox[2 * b + 1].x;
        int cx, cy, cz; cell_of_rt(x, y, z, o, invh, G, cx, cy, cz);
        atomicAdd(&meta[b * G3 + (cz * G + cy) * G + cx], 1u);
    } else {
        t -= PT;
        if (t >= B * N) return;
        const int b = t / N, q = t - b * N;
        const float* qb = xyz + (size_t)b * 3 * N;
        const float x = qb[q] * inv, y = qb[N + q] * inv, z = qb[2 * N + q] * inv;
        const float4 o = bbox[2 * b]; const float invh = bbox[2 * b + 1].x;
        int cx, cy, cz; cell_of_rt(x, y, z, o, invh, G, cx, cy, cz);
        atomicAdd(&qmeta[b * G3 + morton3(cx, cy, cz)], 1u);
    }
}

// ---------------- prep: scan both tables ----------------
__global__ __launch_bounds__(256)
void scan_all_kernel(u32* __restrict__ meta, u32* __restrict__ cursor,
                     u32* __restrict__ qmeta, int G3, int B) {
    const int idx = blockIdx.x, tid = threadIdx.x;
    const bool isQ = idx >= B;
    const int b = isQ ? idx - B : idx;
    u32* arr = (isQ ? qmeta : meta) + b * G3;
    u32* cur = isQ ? nullptr : cursor + b * G3;
    __shared__ u32 tmp[256];
    __shared__ u32 carry;
    if (tid == 0) carry = 0u;
    __syncthreads();
    for (int base = 0; base < G3; base += 256) {       // G3 % 256 == 0
        const u32 c = arr[base + tid];
        tmp[tid] = c;
        __syncthreads();
        for (int s = 1; s < 256; s <<= 1) {
            u32 v = (tid >= s) ? tmp[tid - s] : 0u;
            __syncthreads();
            tmp[tid] += v;
            __syncthreads();
        }
        const u32 start = carry + tmp[tid] - c;        // exclusive
        if (isQ) arr[base + tid] = start;
        else { arr[base + tid] = (start << 16) | c; cur[base + tid] = start; }
        __syncthreads();
        if (tid == 255) carry += tmp[255];
        __syncthreads();
    }
}

// ---------------- prep: scatter points + queries ----------------
__global__ __launch_bounds__(256)
void scatter_all_kernel(const float* __restrict__ sxyz, const float* __restrict__ xyz,
                        const int* __restrict__ rf, int M, int N, int B, int G, int G3,
                        const float4* __restrict__ bbox,
                        u32* __restrict__ cursor, u32* __restrict__ qmeta,
                        float4* __restrict__ pts, u32* __restrict__ qorder) {
    int t = blockIdx.x * 256 + threadIdx.x;
    const float inv = get_inv_sigma(rf);
    const int PT = B * M;
    if (t < PT) {
        const int b = t / M, m = t - b * M;
        const float* sb = sxyz + (size_t)b * 3 * M;
        const float x = sb[m] * inv, y = sb[M + m] * inv, z = sb[2 * M + m] * inv;
        const float4 o = bbox[2 * b]; const float invh = bbox[2 * b + 1].x;
        int cx, cy, cz; cell_of_rt(x, y, z, o, invh, G, cx, cy, cz);
        const u32 pos = atomicAdd(&cursor[b * G3 + (cz * G + cy) * G + cx], 1u);
        pts[(size_t)b * M + pos] = make_float4(x, y, z, __uint_as_float((u32)m));
    } else {
        t -= PT;
        if (t >= B * N) return;
        const int b = t / N, q = t - b * N;
        const float* qb = xyz + (size_t)b * 3 * N;
        const float x = qb[q] * inv, y = qb[N + q] * inv, z = qb[2 * N + q] * inv;
        const float4 o = bbox[2 * b]; const float invh = bbox[2 * b + 1].x;
        int cx, cy, cz; cell_of_rt(x, y, z, o, invh, G, cx, cy, cz);
        const u32 pos = atomicAdd(&qmeta[b * G3 + morton3(cx, cy, cz)], 1u);
        qorder[(size_t)b * N + pos] = (u32)q;
    }
}

// ---------------- search: Morton groups, 4 slice-waves per group ----------------

#define CEK_FULL(k, c) { const bool sw_ = (c) < (k); const u64 mn_ = sw_ ? (c) : (k); \
                         const u64 mx_ = sw_ ? (k) : (c); (k) = mn_; (c) = mx_; }
#define CEK_LAST(k, c) { (k) = ((c) < (k)) ? (c) : (k); }

#define PROC_CAND(p) {                                                        \
    float t_ = qx * (p).x; t_ = fmaf(qy, (p).y, t_); t_ = fmaf(qz, (p).z, t_);\
    const float pw_ = fmaf((p).x, (p).x, fmaf((p).y, (p).y, (p).z * (p).z));  \
    const float dc_ = fmaxf(fmaf(-2.0f, t_, qq + pw_), 1e-12f);               \
    u64 c_ = ((u64)__float_as_uint(dc_) << 32) | (u64)__float_as_uint((p).w); \
    CEK_FULL(k0, c_) CEK_FULL(k1, c_) CEK_FULL(k2, c_) CEK_FULL(k3, c_)       \
    CEK_LAST(k4, c_) }

#define KEY_INIT (((u64)0x7F7FFFFFu) << 32)   // (FLT_MAX, idx 0)
#define SLICES 4

__global__ __launch_bounds__(256)
void sorted_search_kernel(const float* __restrict__ xyz,
                          const float* __restrict__ sflow,
                          const int* __restrict__ rf,
                          const float4* __restrict__ bbox,
                          const u32* __restrict__ meta,
                          const float4* __restrict__ pts,
                          const u32* __restrict__ qorder,
                          float* __restrict__ out,
                          int N, int M, int G, int G3, int bpB) {
    __shared__ u64 mergeK[(SLICES - 1) * KNN * 64];      // 7.5 KB

    const int lane  = threadIdx.x & 63;
    const int wid   = threadIdx.x >> 6;
    const int slice = __builtin_amdgcn_readfirstlane(wid);   // uniform SGPR
    const int g     = blockIdx.x;                            // one group per block
    const int b     = g / bpB;
    const int gi    = g - b * bpB;
    const u32 n     = qorder[(size_t)b * N + gi * 64 + lane];

    const float inv = get_inv_sigma(rf);
    const float* qb = xyz + (size_t)b * 3 * N;
    const float qx = qb[n] * inv;
    const float qy = qb[N + n] * inv;
    const float qz = qb[2 * N + n] * inv;
    const float qq = fmaf(qx, qx, fmaf(qy, qy, qz * qz));

    const float4 o   = bbox[2 * b];
    const float invh = bbox[2 * b + 1].x;
    const float h    = o.w;
    int qcx, qcy, qcz; cell_of_rt(qx, qy, qz, o, invh, G, qcx, qcy, qcz);

    // wave bbox of query cells (all 4 waves hold the same queries -> same bbox)
    int lx = qcx, hx = qcx, ly = qcy, hy = qcy, lz = qcz, hz = qcz;
#pragma unroll
    for (int off = 32; off > 0; off >>= 1) {
        lx = min(lx, __shfl_xor(lx, off, 64)); hx = max(hx, __shfl_xor(hx, off, 64));
        ly = min(ly, __shfl_xor(ly, off, 64)); hy = max(hy, __shfl_xor(hy, off, 64));
        lz = min(lz, __shfl_xor(lz, off, 64)); hz = max(hz, __shfl_xor(hz, off, 64));
    }
    lx = __builtin_amdgcn_readfirstlane(lx); hx = __builtin_amdgcn_readfirstlane(hx);
    ly = __builtin_amdgcn_readfirstlane(ly); hy = __builtin_amdgcn_readfirstlane(hy);
    lz = __builtin_amdgcn_readfirstlane(lz); hz = __builtin_amdgcn_readfirstlane(hz);

    const u32* __restrict__ mb = meta + b * G3;
    const float4* __restrict__ pb = pts + (size_t)b * M;

    u64 k0 = KEY_INIT, k1 = KEY_INIT, k2 = KEY_INIT, k3 = KEY_INIT, k4 = KEY_INIT;
    const float margin = 1e-3f + 1e-5f * qq;
    u32 stripe = 0;                           // uniform; identical across slices

    for (int r = 0; r <= G; ++r) {
        const int ex0 = max(lx - r, 0), ex1 = min(hx + r, G - 1);
        const int ey0 = max(ly - r, 0), ey1 = min(hy + r, G - 1);
        const int ez0 = max(lz - r, 0), ez1 = min(hz + r, G - 1);
        const int px0 = lx - r + 1, px1 = hx + r - 1;   // prev (r-1) unclipped box
        const int py0 = ly - r + 1, py1 = hy + r - 1;
        const int pz0 = lz - r + 1, pz1 = hz + r - 1;
        for (int cz = ez0; cz <= ez1; ++cz) {
            const bool zin = (cz >= pz0 && cz <= pz1);
            for (int cy = ey0; cy <= ey1; ++cy) {
                const bool yin = zin && (cy >= py0 && cy <= py1);
                for (int cx = ex0; cx <= ex1; ++cx) {
                    if (r > 0 && yin && cx >= px0 && cx <= px1) continue; // scanned
                    const u32 s = stripe++ & (SLICES - 1);               // uniform
                    if ((int)s != slice) continue;                       // uniform
                    const u32 mc = mb[(cz * G + cy) * G + cx];  // uniform s_load
                    const u32 cnt = mc & 0xFFFFu;
                    if (!cnt) continue;
                    const u32 st = mc >> 16;
                    u32 i = 0;
                    for (; i + 2 <= cnt; i += 2) {
                        const float4 pa = pb[st + i];
                        const float4 pc = pb[st + i + 1];
                        PROC_CAND(pa)
                        PROC_CAND(pc)
                    }
                    if (i < cnt) { const float4 pa = pb[st + i]; PROC_CAND(pa) }
                }
            }
        }
        // per-slice deterministic stop: every lane's slice-local 5th-best must
        // beat the distance to any cell unscanned by THIS slice (ring > r).
        const float own = __uint_as_float((u32)(k4 >> 32));
        const float bound = (float)r * h;
        if (__all(own < bound * bound - margin)) break;
    }

    if (slice > 0) {
        mergeK[((slice - 1) * KNN + 0) * 64 + lane] = k0;
        mergeK[((slice - 1) * KNN + 1) * 64 + lane] = k1;
        mergeK[((slice - 1) * KNN + 2) * 64 + lane] = k2;
        mergeK[((slice - 1) * KNN + 3) * 64 + lane] = k3;
        mergeK[((slice - 1) * KNN + 4) * 64 + lane] = k4;
    }
    __syncthreads();

    if (slice == 0) {
#pragma unroll
        for (int w = 0; w < SLICES - 1; ++w) {
#pragma unroll
            for (int k = 0; k < KNN; ++k) {
                u64 c = mergeK[(w * KNN + k) * 64 + lane];
                CEK_FULL(k0, c) CEK_FULL(k1, c) CEK_FULL(k2, c) CEK_FULL(k3, c)
                CEK_LAST(k4, c)
            }
        }
        const float d0 = sqrtf(__uint_as_float((u32)(k0 >> 32)));
        const float d1 = sqrtf(__uint_as_float((u32)(k1 >> 32)));
        const float d2 = sqrtf(__uint_as_float((u32)(k2 >> 32)));
        const float d3 = sqrtf(__uint_as_float((u32)(k3 >> 32)));
        const float d4 = sqrtf(__uint_as_float((u32)(k4 >> 32)));
        const float w0 = expf(d0 - d0);
        const float w1 = expf(d0 - d1);
        const float w2 = expf(d0 - d2);
        const float w3 = expf(d0 - d3);
        const float w4 = expf(d0 - d4);
        const float inv_wsum = 1.0f / (w0 + w1 + w2 + w3 + w4);

        const u32 i0 = (u32)k0, i1 = (u32)k1, i2 = (u32)k2, i3 = (u32)k3, i4 = (u32)k4;
        const float* fb = sflow + (size_t)b * 3 * M;
        float ax = 0.f, ay = 0.f, az = 0.f;
        ax = fmaf(w0, fb[i0], ax); ay = fmaf(w0, fb[M + i0], ay); az = fmaf(w0, fb[2 * M + i0], az);
        ax = fmaf(w1, fb[i1], ax); ay = fmaf(w1, fb[M + i1], ay); az = fmaf(w1, fb[2 * M + i1], az);
        ax = fmaf(w2, fb[i2], ax); ay = fmaf(w2, fb[M + i2], ay); az = fmaf(w2, fb[2 * M + i2], az);
        ax = fmaf(w3, fb[i3], ax); ay = fmaf(w3, fb[M + i3], ay); az = fmaf(w3, fb[2 * M + i3], az);
        ax = fmaf(w4, fb[i4], ax); ay = fmaf(w4, fb[M + i4], ay); az = fmaf(w4, fb[2 * M + i4], az);

        float* ob = out + (size_t)b * 3 * N;
        ob[n]         = ax * inv_wsum;
        ob[N + n]     = ay * inv_wsum;
        ob[2 * N + n] = az * inv_wsum;
    }
}

// ---------------- brute-force fallback (r3 structure, no workspace) ----------------

#define CE_FULL(k, ki, c, ci)                          \
    {                                                  \
        const bool sw = (c) < (k);                     \
        const float vmn = fminf(k, c);                 \
        const float vmx = fmaxf(k, c);                 \
        const u32 nki = sw ? (ci) : (ki);              \
        const u32 nci = sw ? (ki) : (ci);              \
        (k) = vmn; (c) = vmx; (ki) = nki; (ci) = nci;  \
    }
#define CE_LAST(k, ki, c, ci)                          \
    {                                                  \
        const bool sw = (c) < (k);                     \
        (ki) = sw ? (ci) : (ki);                       \
        (k) = fminf(k, c);                             \
    }

#define BSLICES 8
__global__ __launch_bounds__(512)
void brute_kernel(const float* __restrict__ xyz, const float* __restrict__ sxyz,
                  const float* __restrict__ sflow, const int* __restrict__ rf,
                  float* __restrict__ out, int N, int M, int bpB) {
    __shared__ float sval_d[BSLICES * KNN * 64];
    __shared__ u32   sval_i[BSLICES * KNN * 64];
    const int tid = threadIdx.x, lane = tid & 63, wid = tid >> 6;
    const int swid = __builtin_amdgcn_readfirstlane(wid);
    const int b = blockIdx.x / bpB;
    const int n = (blockIdx.x % bpB) * 64 + lane;
    const float inv = get_inv_sigma(rf);
    const float* qb = xyz + (size_t)b * 3 * N;
    const float qx = qb[n] * inv, qy = qb[N + n] * inv, qz = qb[2 * N + n] * inv;
    const float qq = fmaf(qx, qx, fmaf(qy, qy, qz * qz));
    const int CH = M / BSLICES, j0 = swid * CH;
    const float* sb = sxyz + (size_t)b * 3 * M;
    float e0 = 1e30f, e1 = 1e30f, e2 = 1e30f, e3 = 1e30f, e4 = 1e30f;
    u32 i0 = 0, i1 = 0, i2 = 0, i3 = 0, i4 = 0;
    for (int j = 0; j < CH; ++j) {
        const float px = sb[j0 + j] * inv;
        const float py = sb[M + j0 + j] * inv;
        const float pz = sb[2 * M + j0 + j] * inv;
        const float pw = fmaf(px, px, fmaf(py, py, pz * pz));
        float t = qx * px; t = fmaf(qy, py, t); t = fmaf(qz, pz, t);
        float c = fmaf(-2.0f, t, pw);
        u32 ci = (u32)(j0 + j);
        CE_FULL(e0, i0, c, ci) CE_FULL(e1, i1, c, ci) CE_FULL(e2, i2, c, ci)
        CE_FULL(e3, i3, c, ci) CE_LAST(e4, i4, c, ci)
    }
    sval_d[(wid * KNN + 0) * 64 + lane] = e0;  sval_i[(wid * KNN + 0) * 64 + lane] = i0;
    sval_d[(wid * KNN + 1) * 64 + lane] = e1;  sval_i[(wid * KNN + 1) * 64 + lane] = i1;
    sval_d[(wid * KNN + 2) * 64 + lane] = e2;  sval_i[(wid * KNN + 2) * 64 + lane] = i2;
    sval_d[(wid * KNN + 3) * 64 + lane] = e3;  sval_i[(wid * KNN + 3) * 64 + lane] = i3;
    sval_d[(wid * KNN + 4) * 64 + lane] = e4;  sval_i[(wid * KNN + 4) * 64 + lane] = i4;
    __syncthreads();
    if (wid == 0) {
        float m0 = 1e30f, m1 = 1e30f, m2 = 1e30f, m3 = 1e30f, m4 = 1e30f;
        u32 g0 = 0, g1 = 0, g2 = 0, g3 = 0, g4 = 0;
#pragma unroll
        for (int w = 0; w < BSLICES; ++w)
#pragma unroll
            for (int k = 0; k < KNN; ++k) {
                float c = sval_d[(w * KNN + k) * 64 + lane];
                u32 ci = sval_i[(w * KNN + k) * 64 + lane];
                CE_FULL(m0, g0, c, ci) CE_FULL(m1, g1, c, ci) CE_FULL(m2, g2, c, ci)
                CE_FULL(m3, g3, c, ci) CE_LAST(m4, g4, c, ci)
            }
        const float d0 = sqrtf(fmaxf(m0 + qq, 1e-12f));
        const float d1 = sqrtf(fmaxf(m1 + qq, 1e-12f));
        const float d2 = sqrtf(fmaxf(m2 + qq, 1e-12f));
        const float d3 = sqrtf(fmaxf(m3 + qq, 1e-12f));
        const float d4 = sqrtf(fmaxf(m4 + qq, 1e-12f));
        const float w0 = expf(d0 - d0), w1 = expf(d0 - d1), w2 = expf(d0 - d2);
        const float w3 = expf(d0 - d3), w4 = expf(d0 - d4);
        const float inv_wsum = 1.0f / (w0 + w1 + w2 + w3 + w4);
        const float* fb = sflow + (size_t)b * 3 * M;
        float ax = 0.f, ay = 0.f, az = 0.f;
        ax = fmaf(w0, fb[g0], ax); ay = fmaf(w0, fb[M + g0], ay); az = fmaf(w0, fb[2 * M + g0], az);
        ax = fmaf(w1, fb[g1], ax); ay = fmaf(w1, fb[M + g1], ay); az = fmaf(w1, fb[2 * M + g1], az);
        ax = fmaf(w2, fb[g2], ax); ay = fmaf(w2, fb[M + g2], ay); az = fmaf(w2, fb[2 * M + g2], az);
        ax = fmaf(w3, fb[g3], ax); ay = fmaf(w3, fb[M + g3], ay); az = fmaf(w3, fb[2 * M + g3], az);
        ax = fmaf(w4, fb[g4], ax); ay = fmaf(w4, fb[M + g4], ay); az = fmaf(w4, fb[2 * M + g4], az);
        float* ob = out + (size_t)b * 3 * N;
        ob[n] = ax * inv_wsum;
        ob[N + n] = ay * inv_wsum;
        ob[2 * N + n] = az * inv_wsum;
    }
}

extern "C" void kernel_launch(void* const* d_in, const int* in_sizes, int n_in,
                              void* d_out, int out_size, void* d_ws, size_t ws_size,
                              hipStream_t stream) {
    const float* xyz   = (const float*)d_in[0];
    const float* sxyz  = (const float*)d_in[1];
    const float* sflow = (const float*)d_in[2];
    const int*   rf    = (const int*)d_in[3];
    // d_in[4] = K; fixed at 5 (KNN).

    const int B = 4;
    const int N = in_sizes[0] / (3 * B);    // 16384
    const int M = in_sizes[1] / (3 * B);    // 4096
    float* out = (float*)d_out;
    const int bpB = N / 64;                 // 256

    // pick grid resolution by workspace budget; power-of-2 G for Morton
    int G = 0;
    {
        const int cand[2] = {16, 8};        // 4096, 512 cells (G3 % 256 == 0)
        for (int ci = 0; ci < 2; ++ci) {
            const int g = cand[ci];
            const size_t g3 = (size_t)g * g * g;
            const size_t need = 128 + 3 * ((size_t)B * g3 * 4)
                              + (size_t)B * M * 16 + (size_t)B * N * 4;
            if (ws_size >= need && g3 % 256 == 0) { G = g; break; }
        }
    }

    if (G > 0 && M <= 65535 && N <= 65535 && (N % 64) == 0) {
        const int G3 = G * G * G;
        char* w = (char*)d_ws;
        float4* bbox   = (float4*)w;                     w += 128;
        u32*    meta   = (u32*)w;                        w += (size_t)B * G3 * 4;
        u32*    cursor = (u32*)w;                        w += (size_t)B * G3 * 4;
        u32*    qmeta  = (u32*)w;                        w += (size_t)B * G3 * 4;
        float4* pts    = (float4*)w;                     w += (size_t)B * M * 16;
        u32*    qorder = (u32*)w;

        const int totalCQ = B * (M + N);
        zero_bbox_kernel<<<dim3(B), dim3(256), 0, stream>>>(sxyz, rf, M, G, G3,
                                                            bbox, meta, cursor, qmeta);
        count_all_kernel<<<dim3((totalCQ + 255) / 256), dim3(256), 0, stream>>>(
            sxyz, xyz, rf, M, N, B, G, G3, bbox, meta, qmeta);
        scan_all_kernel<<<dim3(2 * B), dim3(256), 0, stream>>>(meta, cursor, qmeta, G3, B);
        scatter_all_kernel<<<dim3((totalCQ + 255) / 256), dim3(256), 0, stream>>>(
            sxyz, xyz, rf, M, N, B, G, G3, bbox, cursor, qmeta, pts, qorder);
        const int nGroups = B * bpB;                     // 1024 blocks, 4 waves each
        sorted_search_kernel<<<dim3(nGroups), dim3(256), 0, stream>>>(
            xyz, sflow, rf, bbox, meta, pts, qorder, out, N, M, G, G3, bpB);
    } else {
        brute_kernel<<<dim3(B * bpB), dim3(512), 0, stream>>>(xyz, sxyz, sflow, rf, out, N, M, bpB);
    }
}

// Round 8
// 346.808 us; speedup vs baseline: 8.8239x; 3.9680x over previous
//
#include <hip/hip_runtime.h>
#include <math.h>
#include <stdint.h>

// UpsampleFlow3: fused exact 5-NN + softmax(-dist) + weighted flow sum.
// B=4, N=16384, M=4096, K=5, fp32.
//
// Round-8: cooperative-staging grid search. r7 was latency-dead (8% VALU,
// serial s_load cell walk, ~1pt cells). New structure per Morton query-group
// (64 queries, 1 block = 4 waves):
//   Phase A: 256 threads stage ring-shell cells' points to LDS in PARALLEL
//            (64+ independent loads in flight; LDS atomicAdd placement).
//   Phase B: 4 waves stripe the staged slots; each lane streams the
//            wave-uniform ds_read_b128 broadcast (r1's proven pattern) with
//            the exact u64 (d2bits,idx) CE ladder.
//   Stop:    per-ring merged bound = per-lane min over the 4 stripes' d5
//            (>= true pooled d5) vs (r*h)^2 - margin; block-uniform vote;
//            unconditional break once box covers the grid.
// Output bit-stable: scanned set is always a superset, selection is a total
// order on (d2bits, idx) -> replay-identical despite LDS-atomic placement.

typedef unsigned int u32;
typedef unsigned long long u64;

#define KNN 5
#define G 16
#define G3 4096
#define CAPP 4096          // LDS point capacity = max M (overflow impossible)

__device__ __forceinline__ float get_inv_sigma(const int* __restrict__ rf) {
    const int ri = rf[0];
    const float sigma = (ri >= 1 && ri <= 1000000) ? (float)ri : __int_as_float(ri);
    return 1.0f / sigma;          // INITIAL_RADIUS = 1.0
}

__device__ __forceinline__ void cell_of_rt(float x, float y, float z,
                                           const float4 o, const float invh,
                                           int& cx, int& cy, int& cz) {
    cx = (int)floorf((x - o.x) * invh);
    cy = (int)floorf((y - o.y) * invh);
    cz = (int)floorf((z - o.z) * invh);
    cx = min(max(cx, 0), G - 1);
    cy = min(max(cy, 0), G - 1);
    cz = min(max(cz, 0), G - 1);
}

__device__ __forceinline__ u32 spread5(u32 v) {
    u32 r = (v & 1u);
    r |= (v & 2u) << 2;
    r |= (v & 4u) << 4;
    r |= (v & 8u) << 6;
    r |= (v & 16u) << 8;
    return r;
}
__device__ __forceinline__ u32 morton3(int cx, int cy, int cz) {
    return spread5((u32)cx) | (spread5((u32)cy) << 1) | (spread5((u32)cz) << 2);
}

// ---------------- prep (r4-r7 validated pipeline) ----------------

__global__ __launch_bounds__(256)
void zero_bbox_kernel(const float* __restrict__ sxyz, const int* __restrict__ rf,
                      int M, float4* __restrict__ bbox,
                      u32* __restrict__ meta, u32* __restrict__ cursor,
                      u32* __restrict__ qmeta) {
    const int b = blockIdx.x, tid = threadIdx.x;
    for (int i = tid; i < G3; i += 256) {
        meta[b * G3 + i] = 0u; cursor[b * G3 + i] = 0u; qmeta[b * G3 + i] = 0u;
    }
    const float inv = get_inv_sigma(rf);
    const float* sb = sxyz + (size_t)b * 3 * M;
    float mnx = 1e30f, mny = 1e30f, mnz = 1e30f;
    float mxx = -1e30f, mxy = -1e30f, mxz = -1e30f;
    for (int i = tid; i < M; i += 256) {
        const float x = sb[i] * inv, y = sb[M + i] * inv, z = sb[2 * M + i] * inv;
        mnx = fminf(mnx, x); mxx = fmaxf(mxx, x);
        mny = fminf(mny, y); mxy = fmaxf(mxy, y);
        mnz = fminf(mnz, z); mxz = fmaxf(mxz, z);
    }
    __shared__ float red[6][256];
    red[0][tid] = mnx; red[1][tid] = mny; red[2][tid] = mnz;
    red[3][tid] = mxx; red[4][tid] = mxy; red[5][tid] = mxz;
    __syncthreads();
    for (int s = 128; s > 0; s >>= 1) {
        if (tid < s) {
            red[0][tid] = fminf(red[0][tid], red[0][tid + s]);
            red[1][tid] = fminf(red[1][tid], red[1][tid + s]);
            red[2][tid] = fminf(red[2][tid], red[2][tid + s]);
            red[3][tid] = fmaxf(red[3][tid], red[3][tid + s]);
            red[4][tid] = fmaxf(red[4][tid], red[4][tid + s]);
            red[5][tid] = fmaxf(red[5][tid], red[5][tid + s]);
        }
        __syncthreads();
    }
    if (tid == 0) {
        const float ox = red[0][0], oy = red[1][0], oz = red[2][0];
        const float ext = fmaxf(fmaxf(red[3][0] - ox, red[4][0] - oy), red[5][0] - oz);
        const float h = ext * (1.0f + 2e-5f) / (float)G + 1e-20f;
        bbox[2 * b + 0] = make_float4(ox, oy, oz, h);
        bbox[2 * b + 1] = make_float4(1.0f / h, 0.f, 0.f, 0.f);
    }
}

__global__ __launch_bounds__(256)
void count_all_kernel(const float* __restrict__ sxyz, const float* __restrict__ xyz,
                      const int* __restrict__ rf, int M, int N, int B,
                      const float4* __restrict__ bbox,
                      u32* __restrict__ meta, u32* __restrict__ qmeta) {
    int t = blockIdx.x * 256 + threadIdx.x;
    const float inv = get_inv_sigma(rf);
    const int PT = B * M;
    if (t < PT) {
        const int b = t / M, m = t - b * M;
        const float* sb = sxyz + (size_t)b * 3 * M;
        const float x = sb[m] * inv, y = sb[M + m] * inv, z = sb[2 * M + m] * inv;
        const float4 o = bbox[2 * b]; const float invh = bbox[2 * b + 1].x;
        int cx, cy, cz; cell_of_rt(x, y, z, o, invh, cx, cy, cz);
        atomicAdd(&meta[b * G3 + (cz * G + cy) * G + cx], 1u);
    } else {
        t -= PT;
        if (t >= B * N) return;
        const int b = t / N, q = t - b * N;
        const float* qb = xyz + (size_t)b * 3 * N;
        const float x = qb[q] * inv, y = qb[N + q] * inv, z = qb[2 * N + q] * inv;
        const float4 o = bbox[2 * b]; const float invh = bbox[2 * b + 1].x;
        int cx, cy, cz; cell_of_rt(x, y, z, o, invh, cx, cy, cz);
        atomicAdd(&qmeta[b * G3 + morton3(cx, cy, cz)], 1u);
    }
}

__global__ __launch_bounds__(256)
void scan_all_kernel(u32* __restrict__ meta, u32* __restrict__ cursor,
                     u32* __restrict__ qmeta, int B) {
    const int idx = blockIdx.x, tid = threadIdx.x;
    const bool isQ = idx >= B;
    const int b = isQ ? idx - B : idx;
    u32* arr = (isQ ? qmeta : meta) + b * G3;
    u32* cur = isQ ? nullptr : cursor + b * G3;
    __shared__ u32 tmp[256];
    __shared__ u32 carry;
    if (tid == 0) carry = 0u;
    __syncthreads();
    for (int base = 0; base < G3; base += 256) {
        const u32 c = arr[base + tid];
        tmp[tid] = c;
        __syncthreads();
        for (int s = 1; s < 256; s <<= 1) {
            u32 v = (tid >= s) ? tmp[tid - s] : 0u;
            __syncthreads();
            tmp[tid] += v;
            __syncthreads();
        }
        const u32 start = carry + tmp[tid] - c;
        if (isQ) arr[base + tid] = start;
        else { arr[base + tid] = (start << 16) | c; cur[base + tid] = start; }
        __syncthreads();
        if (tid == 255) carry += tmp[255];
        __syncthreads();
    }
}

__global__ __launch_bounds__(256)
void scatter_all_kernel(const float* __restrict__ sxyz, const float* __restrict__ xyz,
                        const int* __restrict__ rf, int M, int N, int B,
                        const float4* __restrict__ bbox,
                        u32* __restrict__ cursor, u32* __restrict__ qmeta,
                        float4* __restrict__ pts, u32* __restrict__ qorder) {
    int t = blockIdx.x * 256 + threadIdx.x;
    const float inv = get_inv_sigma(rf);
    const int PT = B * M;
    if (t < PT) {
        const int b = t / M, m = t - b * M;
        const float* sb = sxyz + (size_t)b * 3 * M;
        const float x = sb[m] * inv, y = sb[M + m] * inv, z = sb[2 * M + m] * inv;
        const float4 o = bbox[2 * b]; const float invh = bbox[2 * b + 1].x;
        int cx, cy, cz; cell_of_rt(x, y, z, o, invh, cx, cy, cz);
        const u32 pos = atomicAdd(&cursor[b * G3 + (cz * G + cy) * G + cx], 1u);
        pts[(size_t)b * M + pos] = make_float4(x, y, z, __uint_as_float((u32)m));
    } else {
        t -= PT;
        if (t >= B * N) return;
        const int b = t / N, q = t - b * N;
        const float* qb = xyz + (size_t)b * 3 * N;
        const float x = qb[q] * inv, y = qb[N + q] * inv, z = qb[2 * N + q] * inv;
        const float4 o = bbox[2 * b]; const float invh = bbox[2 * b + 1].x;
        int cx, cy, cz; cell_of_rt(x, y, z, o, invh, cx, cy, cz);
        const u32 pos = atomicAdd(&qmeta[b * G3 + morton3(cx, cy, cz)], 1u);
        qorder[(size_t)b * N + pos] = (u32)q;
    }
}

// ---------------- search: cooperative staging + broadcast stream ----------------

#define CEK_FULL(k, c) { const bool sw_ = (c) < (k); const u64 mn_ = sw_ ? (c) : (k); \
                         const u64 mx_ = sw_ ? (k) : (c); (k) = mn_; (c) = mx_; }
#define CEK_LAST(k, c) { (k) = ((c) < (k)) ? (c) : (k); }

#define PROC_CAND(p) {                                                        \
    float t_ = qx * (p).x; t_ = fmaf(qy, (p).y, t_); t_ = fmaf(qz, (p).z, t_);\
    const float pw_ = fmaf((p).x, (p).x, fmaf((p).y, (p).y, (p).z * (p).z));  \
    const float dc_ = fmaxf(fmaf(-2.0f, t_, qq + pw_), 1e-12f);               \
    u64 c_ = ((u64)__float_as_uint(dc_) << 32) | (u64)__float_as_uint((p).w); \
    CEK_FULL(k0, c_) CEK_FULL(k1, c_) CEK_FULL(k2, c_) CEK_FULL(k3, c_)       \
    CEK_LAST(k4, c_) }

#define KEY_INIT (((u64)0x7F7FFFFFu) << 32)   // (FLT_MAX, idx 0)

__global__ __launch_bounds__(256)
void coop_search_kernel(const float* __restrict__ xyz,
                        const float* __restrict__ sflow,
                        const int* __restrict__ rf,
                        const float4* __restrict__ bbox,
                        const u32* __restrict__ meta,
                        const float4* __restrict__ pts,
                        const u32* __restrict__ qorder,
                        float* __restrict__ out,
                        int N, int M, int bpB) {
    __shared__ float4 spts[CAPP];            // 64.0 KB staged candidates
    __shared__ u64    mergeK[3 * KNN * 64];  //  7.5 KB final merge
    __shared__ u32    sbnd[4][64];           //  1.0 KB per-ring stripe d5
    __shared__ u32    tcnt;

    const int tid  = threadIdx.x;
    const int lane = tid & 63;
    const int wid  = tid >> 6;
    const int g    = blockIdx.x;             // one query group per block
    const int b    = g / bpB;
    const int gi   = g - b * bpB;
    const u32 n    = qorder[(size_t)b * N + gi * 64 + lane];

    if (tid == 0) tcnt = 0u;

    const float inv = get_inv_sigma(rf);
    const float* qb = xyz + (size_t)b * 3 * N;
    const float qx = qb[n] * inv;
    const float qy = qb[N + n] * inv;
    const float qz = qb[2 * N + n] * inv;
    const float qq = fmaf(qx, qx, fmaf(qy, qy, qz * qz));

    const float4 o   = bbox[2 * b];
    const float invh = bbox[2 * b + 1].x;
    const float h    = o.w;
    int qcx, qcy, qcz; cell_of_rt(qx, qy, qz, o, invh, qcx, qcy, qcz);

    // group cell bbox (identical in all 4 waves: same 64 queries)
    int lx = qcx, hx = qcx, ly = qcy, hy = qcy, lz = qcz, hz = qcz;
#pragma unroll
    for (int off = 32; off > 0; off >>= 1) {
        lx = min(lx, __shfl_xor(lx, off, 64)); hx = max(hx, __shfl_xor(hx, off, 64));
        ly = min(ly, __shfl_xor(ly, off, 64)); hy = max(hy, __shfl_xor(hy, off, 64));
        lz = min(lz, __shfl_xor(lz, off, 64)); hz = max(hz, __shfl_xor(hz, off, 64));
    }
    lx = __builtin_amdgcn_readfirstlane(lx); hx = __builtin_amdgcn_readfirstlane(hx);
    ly = __builtin_amdgcn_readfirstlane(ly); hy = __builtin_amdgcn_readfirstlane(hy);
    lz = __builtin_amdgcn_readfirstlane(lz); hz = __builtin_amdgcn_readfirstlane(hz);

    const u32* __restrict__ mb = meta + b * G3;
    const float4* __restrict__ pb = pts + (size_t)b * M;

    u64 k0 = KEY_INIT, k1 = KEY_INIT, k2 = KEY_INIT, k3 = KEY_INIT, k4 = KEY_INIT;
    const float margin = 1e-3f + 1e-5f * qq;
    u32 procT = 0;
    __syncthreads();                         // tcnt=0 visible

    for (int r = 0; r <= G; ++r) {
        // ---- phase A: stage ring-r shell cells' points to LDS (parallel) ----
        const int ex0 = max(lx - r, 0), ex1 = min(hx + r, G - 1);
        const int ey0 = max(ly - r, 0), ey1 = min(hy + r, G - 1);
        const int ez0 = max(lz - r, 0), ez1 = min(hz + r, G - 1);
        const int ix0 = max(lx - r + 1, 0), ix1 = min(hx + r - 1, G - 1);  // staged interior
        const int iy0 = max(ly - r + 1, 0), iy1 = min(hy + r - 1, G - 1);
        const int iz0 = max(lz - r + 1, 0), iz1 = min(hz + r - 1, G - 1);
        const int bx = ex1 - ex0 + 1, by = ey1 - ey0 + 1, bz = ez1 - ez0 + 1;
        const int boxN = bx * by * bz;
        for (int t = tid; t < boxN; t += 256) {
            const int cz = ez0 + t / (bx * by);
            const int rem = t - (cz - ez0) * bx * by;
            const int cy = ey0 + rem / bx;
            const int cx = ex0 + rem - (cy - ey0) * bx;
            if (r > 0 && cx >= ix0 && cx <= ix1 && cy >= iy0 && cy <= iy1 &&
                cz >= iz0 && cz <= iz1) continue;          // already staged
            const u32 mc = mb[(cz * G + cy) * G + cx];
            const u32 cnt = mc & 0xFFFFu;
            if (!cnt) continue;
            const u32 st = mc >> 16;
            const u32 pos = atomicAdd(&tcnt, cnt);         // <= M <= CAPP always
            for (u32 i2 = 0; i2 < cnt; ++i2) spts[pos + i2] = pb[st + i2];
        }
        __syncthreads();

        // ---- phase B: stream new slots, striped across the 4 waves ----
        const u32 T = tcnt;
        {
            const u32 off = ((u32)wid - (procT & 3u)) & 3u;
            for (u32 i = procT + off; i < T; i += 4) {
                const float4 p = spts[i];                  // wave-uniform broadcast
                PROC_CAND(p)
            }
        }
        procT = T;

        // ---- merged stop bound: per-lane min over 4 stripes' d5 ----
        sbnd[wid][lane] = (u32)(k4 >> 32);
        __syncthreads();
        const u32 m01 = min(sbnd[0][lane], sbnd[1][lane]);
        const u32 m23 = min(sbnd[2][lane], sbnd[3][lane]);
        const float pooled = __uint_as_float(min(m01, m23));  // >= true pooled d5^2
        const float bound = (float)r * h;
        const bool stop = __all(pooled < bound * bound - margin);   // identical in all waves
        const bool fullcover = (ex0 == 0 && ey0 == 0 && ez0 == 0 &&
                                ex1 == G - 1 && ey1 == G - 1 && ez1 == G - 1);
        __syncthreads();                                   // sbnd reuse next ring
        if (stop || fullcover) break;
    }

    // ---- final merge: waves 1..3 publish, wave 0 merges + epilogue ----
    if (wid > 0) {
        mergeK[((wid - 1) * KNN + 0) * 64 + lane] = k0;
        mergeK[((wid - 1) * KNN + 1) * 64 + lane] = k1;
        mergeK[((wid - 1) * KNN + 2) * 64 + lane] = k2;
        mergeK[((wid - 1) * KNN + 3) * 64 + lane] = k3;
        mergeK[((wid - 1) * KNN + 4) * 64 + lane] = k4;
    }
    __syncthreads();

    if (wid == 0) {
#pragma unroll
        for (int w = 0; w < 3; ++w) {
#pragma unroll
            for (int k = 0; k < KNN; ++k) {
                u64 c = mergeK[(w * KNN + k) * 64 + lane];
                CEK_FULL(k0, c) CEK_FULL(k1, c) CEK_FULL(k2, c) CEK_FULL(k3, c)
                CEK_LAST(k4, c)
            }
        }
        const float d0 = sqrtf(__uint_as_float((u32)(k0 >> 32)));
        const float d1 = sqrtf(__uint_as_float((u32)(k1 >> 32)));
        const float d2 = sqrtf(__uint_as_float((u32)(k2 >> 32)));
        const float d3 = sqrtf(__uint_as_float((u32)(k3 >> 32)));
        const float d4 = sqrtf(__uint_as_float((u32)(k4 >> 32)));
        const float w0 = expf(d0 - d0);
        const float w1 = expf(d0 - d1);
        const float w2 = expf(d0 - d2);
        const float w3 = expf(d0 - d3);
        const float w4 = expf(d0 - d4);
        const float inv_wsum = 1.0f / (w0 + w1 + w2 + w3 + w4);

        const u32 i0 = (u32)k0, i1 = (u32)k1, i2 = (u32)k2, i3 = (u32)k3, i4 = (u32)k4;
        const float* fb = sflow + (size_t)b * 3 * M;
        float ax = 0.f, ay = 0.f, az = 0.f;
        ax = fmaf(w0, fb[i0], ax); ay = fmaf(w0, fb[M + i0], ay); az = fmaf(w0, fb[2 * M + i0], az);
        ax = fmaf(w1, fb[i1], ax); ay = fmaf(w1, fb[M + i1], ay); az = fmaf(w1, fb[2 * M + i1], az);
        ax = fmaf(w2, fb[i2], ax); ay = fmaf(w2, fb[M + i2], ay); az = fmaf(w2, fb[2 * M + i2], az);
        ax = fmaf(w3, fb[i3], ax); ay = fmaf(w3, fb[M + i3], ay); az = fmaf(w3, fb[2 * M + i3], az);
        ax = fmaf(w4, fb[i4], ax); ay = fmaf(w4, fb[M + i4], ay); az = fmaf(w4, fb[2 * M + i4], az);

        float* ob = out + (size_t)b * 3 * N;
        ob[n]         = ax * inv_wsum;
        ob[N + n]     = ay * inv_wsum;
        ob[2 * N + n] = az * inv_wsum;
    }
}

// ---------------- brute-force fallback (r3 structure) ----------------

#define CE_FULL(k, ki, c, ci)                          \
    {                                                  \
        const bool sw = (c) < (k);                     \
        const float vmn = fminf(k, c);                 \
        const float vmx = fmaxf(k, c);                 \
        const u32 nki = sw ? (ci) : (ki);              \
        const u32 nci = sw ? (ki) : (ci);              \
        (k) = vmn; (c) = vmx; (ki) = nki; (ci) = nci;  \
    }
#define CE_LAST(k, ki, c, ci)                          \
    {                                                  \
        const bool sw = (c) < (k);                     \
        (ki) = sw ? (ci) : (ki);                       \
        (k) = fminf(k, c);                             \
    }

#define BSLICES 8
__global__ __launch_bounds__(512)
void brute_kernel(const float* __restrict__ xyz, const float* __restrict__ sxyz,
                  const float* __restrict__ sflow, const int* __restrict__ rf,
                  float* __restrict__ out, int N, int M, int bpB) {
    __shared__ float sval_d[BSLICES * KNN * 64];
    __shared__ u32   sval_i[BSLICES * KNN * 64];
    const int tid = threadIdx.x, lane = tid & 63, wid = tid >> 6;
    const int swid = __builtin_amdgcn_readfirstlane(wid);
    const int b = blockIdx.x / bpB;
    const int n = (blockIdx.x % bpB) * 64 + lane;
    const float inv = get_inv_sigma(rf);
    const float* qb = xyz + (size_t)b * 3 * N;
    const float qx = qb[n] * inv, qy = qb[N + n] * inv, qz = qb[2 * N + n] * inv;
    const float qq = fmaf(qx, qx, fmaf(qy, qy, qz * qz));
    const int CH = M / BSLICES, j0 = swid * CH;
    const float* sb = sxyz + (size_t)b * 3 * M;
    float e0 = 1e30f, e1 = 1e30f, e2 = 1e30f, e3 = 1e30f, e4 = 1e30f;
    u32 i0 = 0, i1 = 0, i2 = 0, i3 = 0, i4 = 0;
    for (int j = 0; j < CH; ++j) {
        const float px = sb[j0 + j] * inv;
        const float py = sb[M + j0 + j] * inv;
        const float pz = sb[2 * M + j0 + j] * inv;
        const float pw = fmaf(px, px, fmaf(py, py, pz * pz));
        float t = qx * px; t = fmaf(qy, py, t); t = fmaf(qz, pz, t);
        float c = fmaf(-2.0f, t, pw);
        u32 ci = (u32)(j0 + j);
        CE_FULL(e0, i0, c, ci) CE_FULL(e1, i1, c, ci) CE_FULL(e2, i2, c, ci)
        CE_FULL(e3, i3, c, ci) CE_LAST(e4, i4, c, ci)
    }
    sval_d[(wid * KNN + 0) * 64 + lane] = e0;  sval_i[(wid * KNN + 0) * 64 + lane] = i0;
    sval_d[(wid * KNN + 1) * 64 + lane] = e1;  sval_i[(wid * KNN + 1) * 64 + lane] = i1;
    sval_d[(wid * KNN + 2) * 64 + lane] = e2;  sval_i[(wid * KNN + 2) * 64 + lane] = i2;
    sval_d[(wid * KNN + 3) * 64 + lane] = e3;  sval_i[(wid * KNN + 3) * 64 + lane] = i3;
    sval_d[(wid * KNN + 4) * 64 + lane] = e4;  sval_i[(wid * KNN + 4) * 64 + lane] = i4;
    __syncthreads();
    if (wid == 0) {
        float m0 = 1e30f, m1 = 1e30f, m2 = 1e30f, m3 = 1e30f, m4 = 1e30f;
        u32 g0 = 0, g1 = 0, g2 = 0, g3 = 0, g4 = 0;
#pragma unroll
        for (int w = 0; w < BSLICES; ++w)
#pragma unroll
            for (int k = 0; k < KNN; ++k) {
                float c = sval_d[(w * KNN + k) * 64 + lane];
                u32 ci = sval_i[(w * KNN + k) * 64 + lane];
                CE_FULL(m0, g0, c, ci) CE_FULL(m1, g1, c, ci) CE_FULL(m2, g2, c, ci)
                CE_FULL(m3, g3, c, ci) CE_LAST(m4, g4, c, ci)
            }
        const float d0 = sqrtf(fmaxf(m0 + qq, 1e-12f));
        const float d1 = sqrtf(fmaxf(m1 + qq, 1e-12f));
        const float d2 = sqrtf(fmaxf(m2 + qq, 1e-12f));
        const float d3 = sqrtf(fmaxf(m3 + qq, 1e-12f));
        const float d4 = sqrtf(fmaxf(m4 + qq, 1e-12f));
        const float w0 = expf(d0 - d0), w1 = expf(d0 - d1), w2 = expf(d0 - d2);
        const float w3 = expf(d0 - d3), w4 = expf(d0 - d4);
        const float inv_wsum = 1.0f / (w0 + w1 + w2 + w3 + w4);
        const float* fb = sflow + (size_t)b * 3 * M;
        float ax = 0.f, ay = 0.f, az = 0.f;
        ax = fmaf(w0, fb[g0], ax); ay = fmaf(w0, fb[M + g0], ay); az = fmaf(w0, fb[2 * M + g0], az);
        ax = fmaf(w1, fb[g1], ax); ay = fmaf(w1, fb[M + g1], ay); az = fmaf(w1, fb[2 * M + g1], az);
        ax = fmaf(w2, fb[g2], ax); ay = fmaf(w2, fb[M + g2], ay); az = fmaf(w2, fb[2 * M + g2], az);
        ax = fmaf(w3, fb[g3], ax); ay = fmaf(w3, fb[M + g3], ay); az = fmaf(w3, fb[2 * M + g3], az);
        ax = fmaf(w4, fb[g4], ax); ay = fmaf(w4, fb[M + g4], ay); az = fmaf(w4, fb[2 * M + g4], az);
        float* ob = out + (size_t)b * 3 * N;
        ob[n] = ax * inv_wsum;
        ob[N + n] = ay * inv_wsum;
        ob[2 * N + n] = az * inv_wsum;
    }
}

extern "C" void kernel_launch(void* const* d_in, const int* in_sizes, int n_in,
                              void* d_out, int out_size, void* d_ws, size_t ws_size,
                              hipStream_t stream) {
    const float* xyz   = (const float*)d_in[0];
    const float* sxyz  = (const float*)d_in[1];
    const float* sflow = (const float*)d_in[2];
    const int*   rf    = (const int*)d_in[3];
    // d_in[4] = K; fixed at 5 (KNN).

    const int B = 4;
    const int N = in_sizes[0] / (3 * B);    // 16384
    const int M = in_sizes[1] / (3 * B);    // 4096
    float* out = (float*)d_out;
    const int bpB = N / 64;                 // 256

    const size_t need = 128 + 3 * ((size_t)B * G3 * 4)
                      + (size_t)B * M * 16 + (size_t)B * N * 4;

    if (ws_size >= need && M <= CAPP && M <= 65535 && (N % 64) == 0) {
        char* w = (char*)d_ws;
        float4* bbox   = (float4*)w;                     w += 128;
        u32*    meta   = (u32*)w;                        w += (size_t)B * G3 * 4;
        u32*    cursor = (u32*)w;                        w += (size_t)B * G3 * 4;
        u32*    qmeta  = (u32*)w;                        w += (size_t)B * G3 * 4;
        float4* pts    = (float4*)w;                     w += (size_t)B * M * 16;
        u32*    qorder = (u32*)w;

        const int totalCQ = B * (M + N);
        zero_bbox_kernel<<<dim3(B), dim3(256), 0, stream>>>(sxyz, rf, M, bbox, meta, cursor, qmeta);
        count_all_kernel<<<dim3((totalCQ + 255) / 256), dim3(256), 0, stream>>>(
            sxyz, xyz, rf, M, N, B, bbox, meta, qmeta);
        scan_all_kernel<<<dim3(2 * B), dim3(256), 0, stream>>>(meta, cursor, qmeta, B);
        scatter_all_kernel<<<dim3((totalCQ + 255) / 256), dim3(256), 0, stream>>>(
            sxyz, xyz, rf, M, N, B, bbox, cursor, qmeta, pts, qorder);
        coop_search_kernel<<<dim3(B * bpB), dim3(256), 0, stream>>>(
            xyz, sflow, rf, bbox, meta, pts, qorder, out, N, M, bpB);
    } else {
        brute_kernel<<<dim3(B * bpB), dim3(512), 0, stream>>>(xyz, sxyz, sflow, rf, out, N, M, bpB);
    }
}